// Round 1
// baseline (864.092 us; speedup 1.0000x reference)
//
#include <hip/hip_runtime.h>

typedef __attribute__((ext_vector_type(8))) short bf16x8;
typedef __attribute__((ext_vector_type(4))) float f32x4;

__device__ __forceinline__ unsigned short f2bf(float f){
  unsigned u = __float_as_uint(f);
  u += 0x7FFFu + ((u >> 16) & 1u);
  return (unsigned short)(u >> 16);
}
__device__ __forceinline__ float bf2f(unsigned short u){
  return __uint_as_float(((unsigned)u) << 16);
}

// ---------------------------------------------------------------------------
// Kernel 1: per-image IoU matching + deterministic balanced sampler + encode
// ---------------------------------------------------------------------------
__global__ __launch_bounds__(256) void match_sample_kernel(
    const float* __restrict__ proposals,   // [8,1000,4]
    const float* __restrict__ gtb,         // [8,64,4]
    const float* __restrict__ gto,         // [8,64,5]
    const int*   __restrict__ gtl,         // [8,64]
    int*   __restrict__ rows_out,          // [4096] global feature row index
    int*   __restrict__ labels_out,        // [4096]
    float* __restrict__ targets_out)       // [4096,5]
{
  const int b = blockIdx.x, t = threadIdx.x;
  __shared__ float g0[64], g1[64], g2[64], g3[64], ga[64];
  __shared__ int glab[64];
  __shared__ int lab_s[1064];
  __shared__ short mid_s[1064];
  __shared__ unsigned char keep_s[1064];
  __shared__ int sidx_s[512];

  if (t < 64){
    const float* gp = gtb + ((size_t)b*64 + t)*4;
    float x0=gp[0], y0=gp[1], x1=gp[2], y1=gp[3];
    g0[t]=x0; g1[t]=y0; g2[t]=x1; g3[t]=y1;
    ga[t] = (x1-x0)*(y1-y0);
    glab[t] = gtl[b*64 + t];
  }
  __syncthreads();

  for (int i=t; i<1064; i+=256){
    float p0,p1,p2,p3;
    if (i < 1000){
      const float* pp = proposals + ((size_t)b*1000 + i)*4;
      p0=pp[0]; p1=pp[1]; p2=pp[2]; p3=pp[3];
    } else {
      const float* pp = gtb + ((size_t)b*64 + (i-1000))*4;
      p0=pp[0]; p1=pp[1]; p2=pp[2]; p3=pp[3];
    }
    float pa = (p2-p0)*(p3-p1);
    float best = -1.f; int bi = 0;
    for (int g=0; g<64; g++){
      float w = fminf(g2[g], p2) - fmaxf(g0[g], p0);
      float h = fminf(g3[g], p3) - fmaxf(g1[g], p1);
      w = fmaxf(w, 0.f); h = fmaxf(h, 0.f);
      float inter = w*h;
      float iou = inter / (ga[g] + pa - inter);
      if (iou > best){ best = iou; bi = g; }   // first-argmax semantics
    }
    lab_s[i] = (best < 0.3f) ? 0 : ((best < 0.5f) ? -1 : glab[bi]);
    mid_s[i] = (short)((best < 0.5f) ? 0 : bi);  // clamped matched idx
  }
  __syncthreads();

  // Deterministic sampler: wave 0 only (ballot/popc scans over 17 chunks).
  if (t < 64){
    const unsigned long long below = (1ull << t) - 1ull;
    int totpos = 0;
    for (int c=0; c<17; c++){
      int i = c*64 + t;
      bool pos = (i < 1064) && (lab_s[i] > 0);
      totpos += __popcll(__ballot(pos));
    }
    const int budget = 512 - min(totpos, 128);
    int cp=0, cn=0, k=0;
    for (int c=0; c<17; c++){
      int i = c*64 + t;
      bool valid = i < 1064;
      int lab = valid ? lab_s[i] : -1;
      bool pos = valid && (lab > 0);
      bool neg = valid && (lab == 0);
      unsigned long long mp = __ballot(pos);
      unsigned long long mn = __ballot(neg);
      bool keep = (pos && (cp + __popcll(mp & below) + 1 <= 128))
               || (neg && (cn + __popcll(mn & below) + 1 <= budget));
      unsigned long long mk = __ballot(keep);
      if (valid) keep_s[i] = keep ? 1 : 0;
      if (keep) sidx_s[k + __popcll(mk & below)] = i;
      cp += __popcll(mp); cn += __popcll(mn); k += __popcll(mk);
    }
    // fill remaining slots with lowest-index non-kept (top_k tie behavior)
    for (int c=0; c<17; c++){
      if (k >= 512) break;
      int i = c*64 + t;
      bool un = (i < 1064) && !keep_s[i];
      unsigned long long mu = __ballot(un);
      if (un){
        int pi = k + __popcll(mu & below);
        if (pi < 512) sidx_s[pi] = i;
      }
      k += __popcll(mu);
    }
  }
  __syncthreads();

  for (int s=t; s<512; s+=256){
    int i = sidx_s[s];
    int orow = b*512 + s;
    labels_out[orow] = lab_s[i];
    rows_out[orow] = b*1064 + i;
    float p0,p1,p2,p3;
    if (i < 1000){
      const float* pp = proposals + ((size_t)b*1000 + i)*4;
      p0=pp[0]; p1=pp[1]; p2=pp[2]; p3=pp[3];
    } else {
      const float* pp = gtb + ((size_t)b*64 + (i-1000))*4;
      p0=pp[0]; p1=pp[1]; p2=pp[2]; p3=pp[3];
    }
    const float* ob = gto + ((size_t)b*64 + (int)mid_s[i])*5;
    float pw = p2-p0, ph = p3-p1;
    float pcx = p0 + 0.5f*pw, pcy = p1 + 0.5f*ph;
    float* tg = targets_out + (size_t)orow*5;
    tg[0] = 10.f*(ob[0]-pcx)/pw;
    tg[1] = 10.f*(ob[1]-pcy)/ph;
    tg[2] = 5.f*logf(ob[2]/pw);
    tg[3] = 5.f*logf(ob[3]/ph);
    tg[4] = 10.f*ob[4];
  }
}

// ---------------------------------------------------------------------------
// Transpose + f32->bf16 convert: src [R][C] f32 -> dst [C][R] bf16
// ---------------------------------------------------------------------------
__global__ __launch_bounds__(256) void transpose_cvt(const float* __restrict__ src,
    unsigned short* __restrict__ dst, int R, int C)
{
  __shared__ float tile[32][33];
  int rb = blockIdx.x*32, cb = blockIdx.y*32;
  int tx = threadIdx.x, ty = threadIdx.y;
  #pragma unroll
  for (int i=0;i<4;i++)
    tile[ty+8*i][tx] = src[(size_t)(rb+ty+8*i)*C + cb+tx];
  __syncthreads();
  #pragma unroll
  for (int i=0;i<4;i++)
    dst[(size_t)(cb+ty+8*i)*R + rb+tx] = f2bf(tile[tx][ty+8*i]);
}

// W3T[96][1024] bf16 from cls_w [1024,16] and reg_w [1024,80]
__global__ void w3_cvt(const float* __restrict__ clsw, const float* __restrict__ regw,
                       unsigned short* __restrict__ dst)
{
  int n = blockIdx.x; // 0..95
  for (int k=threadIdx.x; k<1024; k+=256){
    float v = (n<16) ? clsw[(size_t)k*16+n] : regw[(size_t)k*80 + (n-16)];
    dst[(size_t)n*1024 + k] = f2bf(v);
  }
}

// gather sampled feature rows -> bf16 X [4096][12544]
__global__ __launch_bounds__(256) void gather_cvt(const float* __restrict__ feat,
    const int* __restrict__ rows, unsigned short* __restrict__ X)
{
  int o = blockIdx.x;
  const float4* s = (const float4*)(feat + (size_t)rows[o]*12544);
  ushort4* d = (ushort4*)(X + (size_t)o*12544);
  for (int i=threadIdx.x; i<3136; i+=256){
    float4 v = s[i];
    ushort4 u;
    u.x = f2bf(v.x); u.y = f2bf(v.y); u.z = f2bf(v.z); u.w = f2bf(v.w);
    d[i] = u;
  }
}

// ---------------------------------------------------------------------------
// bf16 MFMA GEMM: C[z] = A[M,K-slice] * B^T   (A,B K-contiguous bf16)
// 128x128 tile, BK=64, 4 waves (2x2), global_load_lds width 16, split-K via z
// ---------------------------------------------------------------------------
__global__ __launch_bounds__(256) void gemm_bf16(
    const unsigned short* __restrict__ A, const unsigned short* __restrict__ Bm,
    float* __restrict__ C, int K, int kPer, size_t cStride)
{
  __shared__ unsigned short As[128*64];
  __shared__ unsigned short Bs[128*64];
  const int tid = threadIdx.x;
  const int wid = tid >> 6, lane = tid & 63;
  const int bm = blockIdx.x * 128, bn = blockIdx.y * 128;
  const int z = blockIdx.z;
  const int N = gridDim.y * 128;
  float* Cp = C + (size_t)z * cStride;
  f32x4 acc[4][4] = {};
  const int rowb = tid >> 3;
  const int colc = (tid & 7) * 8;
  const int k0 = z * kPer;
  const int wm = (wid>>1)*64, wn = (wid&1)*64;
  const int r = lane & 15;

  for (int kt = 0; kt < kPer; kt += 64){
    const int kk = k0 + kt;
    #pragma unroll
    for (int j=0;j<4;j++){
      int row = j*32 + rowb;
      const unsigned short* gaddr = A + (size_t)(bm+row)*K + kk + colc;
      const unsigned short* gbddr = Bm + (size_t)(bn+row)*K + kk + colc;
      __builtin_amdgcn_global_load_lds(
          (const __attribute__((address_space(1))) void*)gaddr,
          (__attribute__((address_space(3))) void*)(As + (size_t)(j*256 + wid*64)*8),
          16, 0, 0);
      __builtin_amdgcn_global_load_lds(
          (const __attribute__((address_space(1))) void*)gbddr,
          (__attribute__((address_space(3))) void*)(Bs + (size_t)(j*256 + wid*64)*8),
          16, 0, 0);
    }
    __syncthreads();
    #pragma unroll
    for (int ks=0; ks<2; ks++){
      const int kq = ks*32 + (lane>>4)*8;
      bf16x8 af[4], bfr[4];
      #pragma unroll
      for (int i=0;i<4;i++){
        af[i]  = *(const bf16x8*)(As + (wm + i*16 + r)*64 + kq);
        bfr[i] = *(const bf16x8*)(Bs + (wn + i*16 + r)*64 + kq);
      }
      #pragma unroll
      for (int i=0;i<4;i++)
        #pragma unroll
        for (int n2=0;n2<4;n2++)
          acc[i][n2] = __builtin_amdgcn_mfma_f32_16x16x32_bf16(af[i], bfr[n2], acc[i][n2], 0,0,0);
    }
    __syncthreads();
  }
  const int crow = (lane>>4)*4, ccol = lane & 15;
  #pragma unroll
  for (int i=0;i<4;i++)
    #pragma unroll
    for (int n2=0;n2<4;n2++)
      #pragma unroll
      for (int q=0;q<4;q++)
        Cp[(size_t)(bm + wm + i*16 + crow + q)*N + (bn + wn + n2*16 + ccol)] = acc[i][n2][q];
}

// sum split-K partials + bias + relu -> bf16
__global__ __launch_bounds__(256) void bias_relu_cvt(const float* __restrict__ Ca,
    const float* __restrict__ Cb, const float* __restrict__ bias,
    unsigned short* __restrict__ Hout)
{
  int idx = blockIdx.x*256 + threadIdx.x;       // float4 index, 1M total
  float4 a = ((const float4*)Ca)[idx];
  float4 b = ((const float4*)Cb)[idx];
  float4 bs = ((const float4*)bias)[idx & 255]; // 1024/4 bias vectors
  ushort4 o;
  o.x = f2bf(fmaxf(a.x+b.x+bs.x, 0.f));
  o.y = f2bf(fmaxf(a.y+b.y+bs.y, 0.f));
  o.z = f2bf(fmaxf(a.z+b.z+bs.z, 0.f));
  o.w = f2bf(fmaxf(a.w+b.w+bs.w, 0.f));
  ((ushort4*)Hout)[idx] = o;
}

// heads: OUT3[4096][96] = H2[4096][1024] @ W3T[96][1024]^T + bias
__global__ __launch_bounds__(256) void head_gemm(const unsigned short* __restrict__ H2,
    const unsigned short* __restrict__ W3T, const float* __restrict__ clsb,
    const float* __restrict__ regb, float* __restrict__ OUT3)
{
  __shared__ unsigned short hs[16*1032];        // +8 pad breaks bank conflicts
  int t = threadIdx.x;
  int r0 = blockIdx.x * 16;
  for (int c = t; c < 2048; c += 256){
    int row = c >> 7;
    int col = (c & 127) * 8;
    *(uint4*)(hs + row*1032 + col) = *(const uint4*)(H2 + (size_t)(r0+row)*1024 + col);
  }
  __syncthreads();
  int r = t & 15;
  int nb = (t >> 4) * 6;
  float acc[6] = {0,0,0,0,0,0};
  for (int k = 0; k < 1024; k += 8){
    bf16x8 hv = *(const bf16x8*)(hs + r*1032 + k);
    float hf[8];
    #pragma unroll
    for (int e=0;e<8;e++) hf[e] = bf2f((unsigned short)hv[e]);
    #pragma unroll
    for (int j=0;j<6;j++){
      bf16x8 wv = *(const bf16x8*)(W3T + (size_t)(nb+j)*1024 + k);
      #pragma unroll
      for (int e=0;e<8;e++) acc[j] += hf[e] * bf2f((unsigned short)wv[e]);
    }
  }
  #pragma unroll
  for (int j=0;j<6;j++){
    int n = nb + j;
    float bias = (n<16) ? clsb[n] : regb[n-16];
    OUT3[(size_t)(r0+r)*96 + n] = acc[j] + bias;
  }
}

// losses: per-row softmax CE + masked smooth-L1, deterministic 2-stage reduce
__global__ __launch_bounds__(256) void loss_partial(const float* __restrict__ OUT3,
    const int* __restrict__ labels, const float* __restrict__ targets,
    float* __restrict__ partials)
{
  int row = blockIdx.x*256 + threadIdx.x;
  float lc, lr = 0.f;
  {
    const float* o = OUT3 + (size_t)row*96;
    int lab = labels[row];
    float m = o[0];
    #pragma unroll
    for (int j=1;j<16;j++) m = fmaxf(m, o[j]);
    float s = 0.f;
    #pragma unroll
    for (int j=0;j<16;j++) s += expf(o[j]-m);
    float lse = logf(s) + m;
    int li = (lab < 0) ? (lab + 16) : lab;   // JAX negative-index wrap
    lc = lse - o[li];
    if (lab > 0){
      const float* tg = targets + (size_t)row*5;
      #pragma unroll
      for (int j=0;j<5;j++){
        float d = fabsf(o[16 + lab*5 + j] - tg[j]);
        lr += (d < (1.f/9.f)) ? (4.5f*d*d) : (d - (1.f/18.f));
      }
    }
  }
  #pragma unroll
  for (int off=32; off>0; off>>=1){
    lc += __shfl_down(lc, off);
    lr += __shfl_down(lr, off);
  }
  __shared__ float red[8];
  int w = threadIdx.x >> 6;
  if ((threadIdx.x & 63) == 0){ red[w] = lc; red[4+w] = lr; }
  __syncthreads();
  if (threadIdx.x == 0){
    partials[blockIdx.x*2]   = red[0]+red[1]+red[2]+red[3];
    partials[blockIdx.x*2+1] = red[4]+red[5]+red[6]+red[7];
  }
}

__global__ void loss_final(const float* __restrict__ partials, float* __restrict__ out){
  if (threadIdx.x == 0){
    float a = 0.f, b = 0.f;
    for (int i=0;i<16;i++){ a += partials[2*i]; b += partials[2*i+1]; }
    out[0] = a * (1.f/4096.f);
    out[1] = b * (1.f/4096.f);
  }
}

// ---------------------------------------------------------------------------
extern "C" void kernel_launch(void* const* d_in, const int* in_sizes, int n_in,
                              void* d_out, int out_size, void* d_ws, size_t ws_size,
                              hipStream_t stream)
{
  const float* proposals = (const float*)d_in[0];
  const float* gtb  = (const float*)d_in[1];
  const float* gto  = (const float*)d_in[2];
  const int*   gtl  = (const int*)d_in[3];
  const float* feat = (const float*)d_in[4];
  const float* fc1w = (const float*)d_in[5];
  const float* fc1b = (const float*)d_in[6];
  const float* fc2w = (const float*)d_in[7];
  const float* fc2b = (const float*)d_in[8];
  const float* clsw = (const float*)d_in[9];
  const float* clsb = (const float*)d_in[10];
  const float* regw = (const float*)d_in[11];
  const float* regb = (const float*)d_in[12];

  unsigned char* p = (unsigned char*)d_ws;
  auto alloc = [&](size_t bytes)->unsigned char*{
    unsigned char* r = p; p += (bytes + 255) & ~(size_t)255; return r;
  };
  unsigned short* X   = (unsigned short*)alloc((size_t)4096*12544*2);
  unsigned short* W1T = (unsigned short*)alloc((size_t)1024*12544*2);
  unsigned short* W2T = (unsigned short*)alloc((size_t)1024*1024*2);
  unsigned short* W3T = (unsigned short*)alloc((size_t)96*1024*2);
  float*          C   = (float*)alloc((size_t)2*4096*1024*4);   // split-K partials
  unsigned short* H1  = (unsigned short*)alloc((size_t)4096*1024*2);
  unsigned short* H2  = (unsigned short*)alloc((size_t)4096*1024*2);
  float*          OUT3= (float*)alloc((size_t)4096*96*4);
  float*       targets= (float*)alloc((size_t)4096*5*4);
  int*          labels= (int*)alloc((size_t)4096*4);
  int*            rows= (int*)alloc((size_t)4096*4);
  float*      partials= (float*)alloc((size_t)16*2*4);

  match_sample_kernel<<<8, 256, 0, stream>>>(proposals, gtb, gto, gtl, rows, labels, targets);
  transpose_cvt<<<dim3(392,32), dim3(32,8), 0, stream>>>(fc1w, W1T, 12544, 1024);
  transpose_cvt<<<dim3(32,32),  dim3(32,8), 0, stream>>>(fc2w, W2T, 1024, 1024);
  w3_cvt<<<96, 256, 0, stream>>>(clsw, regw, W3T);
  gather_cvt<<<4096, 256, 0, stream>>>(feat, rows, X);

  gemm_bf16<<<dim3(32,8,2), 256, 0, stream>>>(X, W1T, C, 12544, 6272, (size_t)4096*1024);
  bias_relu_cvt<<<4096, 256, 0, stream>>>(C, C + (size_t)4096*1024, fc1b, H1);

  gemm_bf16<<<dim3(32,8,2), 256, 0, stream>>>(H1, W2T, C, 1024, 512, (size_t)4096*1024);
  bias_relu_cvt<<<4096, 256, 0, stream>>>(C, C + (size_t)4096*1024, fc2b, H2);

  head_gemm<<<256, 256, 0, stream>>>(H2, W3T, clsb, regb, OUT3);
  loss_partial<<<16, 256, 0, stream>>>(OUT3, labels, targets, partials);
  loss_final<<<1, 64, 0, stream>>>(partials, (float*)d_out);
}

// Round 2
// 846.967 us; speedup vs baseline: 1.0202x; 1.0202x over previous
//
#include <hip/hip_runtime.h>

typedef __attribute__((ext_vector_type(8))) short bf16x8;
typedef __attribute__((ext_vector_type(4))) float f32x4;

__device__ __forceinline__ unsigned short f2bf(float f){
  unsigned u = __float_as_uint(f);
  u += 0x7FFFu + ((u >> 16) & 1u);
  return (unsigned short)(u >> 16);
}
__device__ __forceinline__ float bf2f(unsigned short u){
  return __uint_as_float(((unsigned)u) << 16);
}

// ---------------------------------------------------------------------------
// Kernel 1: per-image IoU matching + deterministic balanced sampler + encode
// ---------------------------------------------------------------------------
__global__ __launch_bounds__(256) void match_sample_kernel(
    const float* __restrict__ proposals,   // [8,1000,4]
    const float* __restrict__ gtb,         // [8,64,4]
    const float* __restrict__ gto,         // [8,64,5]
    const int*   __restrict__ gtl,         // [8,64]
    int*   __restrict__ rows_out,          // [4096] global feature row index
    int*   __restrict__ labels_out,        // [4096]
    float* __restrict__ targets_out)       // [4096,5]
{
  const int b = blockIdx.x, t = threadIdx.x;
  __shared__ float g0[64], g1[64], g2[64], g3[64], ga[64];
  __shared__ int glab[64];
  __shared__ int lab_s[1064];
  __shared__ short mid_s[1064];
  __shared__ unsigned char keep_s[1064];
  __shared__ int sidx_s[512];

  if (t < 64){
    const float* gp = gtb + ((size_t)b*64 + t)*4;
    float x0=gp[0], y0=gp[1], x1=gp[2], y1=gp[3];
    g0[t]=x0; g1[t]=y0; g2[t]=x1; g3[t]=y1;
    ga[t] = (x1-x0)*(y1-y0);
    glab[t] = gtl[b*64 + t];
  }
  __syncthreads();

  for (int i=t; i<1064; i+=256){
    float p0,p1,p2,p3;
    if (i < 1000){
      const float* pp = proposals + ((size_t)b*1000 + i)*4;
      p0=pp[0]; p1=pp[1]; p2=pp[2]; p3=pp[3];
    } else {
      const float* pp = gtb + ((size_t)b*64 + (i-1000))*4;
      p0=pp[0]; p1=pp[1]; p2=pp[2]; p3=pp[3];
    }
    float pa = (p2-p0)*(p3-p1);
    float best = -1.f; int bi = 0;
    for (int g=0; g<64; g++){
      float w = fminf(g2[g], p2) - fmaxf(g0[g], p0);
      float h = fminf(g3[g], p3) - fmaxf(g1[g], p1);
      w = fmaxf(w, 0.f); h = fmaxf(h, 0.f);
      float inter = w*h;
      float iou = inter / (ga[g] + pa - inter);
      if (iou > best){ best = iou; bi = g; }   // first-argmax semantics
    }
    lab_s[i] = (best < 0.3f) ? 0 : ((best < 0.5f) ? -1 : glab[bi]);
    mid_s[i] = (short)((best < 0.5f) ? 0 : bi);  // clamped matched idx
  }
  __syncthreads();

  // Deterministic sampler: wave 0 only (ballot/popc scans over 17 chunks).
  if (t < 64){
    const unsigned long long below = (1ull << t) - 1ull;
    int totpos = 0;
    for (int c=0; c<17; c++){
      int i = c*64 + t;
      bool pos = (i < 1064) && (lab_s[i] > 0);
      totpos += __popcll(__ballot(pos));
    }
    const int budget = 512 - min(totpos, 128);
    int cp=0, cn=0, k=0;
    for (int c=0; c<17; c++){
      int i = c*64 + t;
      bool valid = i < 1064;
      int lab = valid ? lab_s[i] : -1;
      bool pos = valid && (lab > 0);
      bool neg = valid && (lab == 0);
      unsigned long long mp = __ballot(pos);
      unsigned long long mn = __ballot(neg);
      bool keep = (pos && (cp + __popcll(mp & below) + 1 <= 128))
               || (neg && (cn + __popcll(mn & below) + 1 <= budget));
      unsigned long long mk = __ballot(keep);
      if (valid) keep_s[i] = keep ? 1 : 0;
      if (keep) sidx_s[k + __popcll(mk & below)] = i;
      cp += __popcll(mp); cn += __popcll(mn); k += __popcll(mk);
    }
    // fill remaining slots with lowest-index non-kept (top_k tie behavior)
    for (int c=0; c<17; c++){
      if (k >= 512) break;
      int i = c*64 + t;
      bool un = (i < 1064) && !keep_s[i];
      unsigned long long mu = __ballot(un);
      if (un){
        int pi = k + __popcll(mu & below);
        if (pi < 512) sidx_s[pi] = i;
      }
      k += __popcll(mu);
    }
  }
  __syncthreads();

  for (int s=t; s<512; s+=256){
    int i = sidx_s[s];
    int orow = b*512 + s;
    labels_out[orow] = lab_s[i];
    rows_out[orow] = b*1064 + i;
    float p0,p1,p2,p3;
    if (i < 1000){
      const float* pp = proposals + ((size_t)b*1000 + i)*4;
      p0=pp[0]; p1=pp[1]; p2=pp[2]; p3=pp[3];
    } else {
      const float* pp = gtb + ((size_t)b*64 + (i-1000))*4;
      p0=pp[0]; p1=pp[1]; p2=pp[2]; p3=pp[3];
    }
    const float* ob = gto + ((size_t)b*64 + (int)mid_s[i])*5;
    float pw = p2-p0, ph = p3-p1;
    float pcx = p0 + 0.5f*pw, pcy = p1 + 0.5f*ph;
    float* tg = targets_out + (size_t)orow*5;
    tg[0] = 10.f*(ob[0]-pcx)/pw;
    tg[1] = 10.f*(ob[1]-pcy)/ph;
    tg[2] = 5.f*logf(ob[2]/pw);
    tg[3] = 5.f*logf(ob[3]/ph);
    tg[4] = 10.f*ob[4];
  }
}

// ---------------------------------------------------------------------------
// Transpose + f32->bf16 convert: src [R][C] f32 -> dst [C][R] bf16
// ---------------------------------------------------------------------------
__global__ __launch_bounds__(256) void transpose_cvt(const float* __restrict__ src,
    unsigned short* __restrict__ dst, int R, int C)
{
  __shared__ float tile[32][33];
  int rb = blockIdx.x*32, cb = blockIdx.y*32;
  int tx = threadIdx.x, ty = threadIdx.y;
  #pragma unroll
  for (int i=0;i<4;i++)
    tile[ty+8*i][tx] = src[(size_t)(rb+ty+8*i)*C + cb+tx];
  __syncthreads();
  #pragma unroll
  for (int i=0;i<4;i++)
    dst[(size_t)(cb+ty+8*i)*R + rb+tx] = f2bf(tile[tx][ty+8*i]);
}

// W3T[96][1024] bf16 from cls_w [1024,16] and reg_w [1024,80]
__global__ void w3_cvt(const float* __restrict__ clsw, const float* __restrict__ regw,
                       unsigned short* __restrict__ dst)
{
  int n = blockIdx.x; // 0..95
  for (int k=threadIdx.x; k<1024; k+=256){
    float v = (n<16) ? clsw[(size_t)k*16+n] : regw[(size_t)k*80 + (n-16)];
    dst[(size_t)n*1024 + k] = f2bf(v);
  }
}

// ---------------------------------------------------------------------------
// fc1 GEMM with fused row-gather + f32->bf16 convert on the A operand.
// C[z] = feat[rows][k0:k0+kPer] (cvt bf16) @ W1T^T ; 128x128 tile, BK=64,
// 4 waves (2x2), A reg-staged, B via global_load_lds width 16, split-K via z.
// ---------------------------------------------------------------------------
__global__ __launch_bounds__(256) void gemm_fc1(
    const float* __restrict__ feat, const int* __restrict__ rows,
    const unsigned short* __restrict__ Bm,
    float* __restrict__ C, int K, int kPer, size_t cStride)
{
  __shared__ unsigned short As[128*64];
  __shared__ unsigned short Bs[128*64];
  __shared__ int ridx[128];
  const int tid = threadIdx.x;
  const int wid = tid >> 6, lane = tid & 63;
  const int bm = blockIdx.x * 128, bn = blockIdx.y * 128;
  const int z = blockIdx.z;
  const int N = gridDim.y * 128;
  float* Cp = C + (size_t)z * cStride;
  f32x4 acc[4][4] = {};
  const int rowb = tid >> 3;          // 0..31
  const int colc = (tid & 7) * 8;     // 0..56 step 8 (elements)
  const int k0 = z * kPer;
  const int wm = (wid>>1)*64, wn = (wid&1)*64;
  const int r = lane & 15;

  if (tid < 128) ridx[tid] = rows[bm + tid];
  __syncthreads();

  for (int kt = 0; kt < kPer; kt += 64){
    const int kk = k0 + kt;
    // B: async global->LDS
    #pragma unroll
    for (int j=0;j<4;j++){
      int row = j*32 + rowb;
      const unsigned short* gbddr = Bm + (size_t)(bn+row)*K + kk + colc;
      __builtin_amdgcn_global_load_lds(
          (const __attribute__((address_space(1))) void*)gbddr,
          (__attribute__((address_space(3))) void*)(Bs + (size_t)(j*256 + wid*64)*8),
          16, 0, 0);
    }
    // A: gather f32 rows, convert, LDS write
    #pragma unroll
    for (int j=0;j<4;j++){
      int row = j*32 + rowb;
      const float* ap = feat + (size_t)ridx[row]*12544 + kk + colc;
      float4 v0 = *(const float4*)ap;
      float4 v1 = *(const float4*)(ap + 4);
      uint4 w;
      w.x = (unsigned)f2bf(v0.x) | ((unsigned)f2bf(v0.y) << 16);
      w.y = (unsigned)f2bf(v0.z) | ((unsigned)f2bf(v0.w) << 16);
      w.z = (unsigned)f2bf(v1.x) | ((unsigned)f2bf(v1.y) << 16);
      w.w = (unsigned)f2bf(v1.z) | ((unsigned)f2bf(v1.w) << 16);
      *(uint4*)(As + (size_t)row*64 + colc) = w;
    }
    __syncthreads();
    #pragma unroll
    for (int ks=0; ks<2; ks++){
      const int kq = ks*32 + (lane>>4)*8;
      bf16x8 af[4], bfr[4];
      #pragma unroll
      for (int i=0;i<4;i++){
        af[i]  = *(const bf16x8*)(As + (wm + i*16 + r)*64 + kq);
        bfr[i] = *(const bf16x8*)(Bs + (wn + i*16 + r)*64 + kq);
      }
      #pragma unroll
      for (int i=0;i<4;i++)
        #pragma unroll
        for (int n2=0;n2<4;n2++)
          acc[i][n2] = __builtin_amdgcn_mfma_f32_16x16x32_bf16(af[i], bfr[n2], acc[i][n2], 0,0,0);
    }
    __syncthreads();
  }
  const int crow = (lane>>4)*4, ccol = lane & 15;
  #pragma unroll
  for (int i=0;i<4;i++)
    #pragma unroll
    for (int n2=0;n2<4;n2++)
      #pragma unroll
      for (int q=0;q<4;q++)
        Cp[(size_t)(bm + wm + i*16 + crow + q)*N + (bn + wn + n2*16 + ccol)] = acc[i][n2][q];
}

// ---------------------------------------------------------------------------
// bf16 MFMA GEMM (both operands bf16, K-contiguous): used for fc2
// ---------------------------------------------------------------------------
__global__ __launch_bounds__(256) void gemm_bf16(
    const unsigned short* __restrict__ A, const unsigned short* __restrict__ Bm,
    float* __restrict__ C, int K, int kPer, size_t cStride)
{
  __shared__ unsigned short As[128*64];
  __shared__ unsigned short Bs[128*64];
  const int tid = threadIdx.x;
  const int wid = tid >> 6, lane = tid & 63;
  const int bm = blockIdx.x * 128, bn = blockIdx.y * 128;
  const int z = blockIdx.z;
  const int N = gridDim.y * 128;
  float* Cp = C + (size_t)z * cStride;
  f32x4 acc[4][4] = {};
  const int rowb = tid >> 3;
  const int colc = (tid & 7) * 8;
  const int k0 = z * kPer;
  const int wm = (wid>>1)*64, wn = (wid&1)*64;
  const int r = lane & 15;

  for (int kt = 0; kt < kPer; kt += 64){
    const int kk = k0 + kt;
    #pragma unroll
    for (int j=0;j<4;j++){
      int row = j*32 + rowb;
      const unsigned short* gaddr = A + (size_t)(bm+row)*K + kk + colc;
      const unsigned short* gbddr = Bm + (size_t)(bn+row)*K + kk + colc;
      __builtin_amdgcn_global_load_lds(
          (const __attribute__((address_space(1))) void*)gaddr,
          (__attribute__((address_space(3))) void*)(As + (size_t)(j*256 + wid*64)*8),
          16, 0, 0);
      __builtin_amdgcn_global_load_lds(
          (const __attribute__((address_space(1))) void*)gbddr,
          (__attribute__((address_space(3))) void*)(Bs + (size_t)(j*256 + wid*64)*8),
          16, 0, 0);
    }
    __syncthreads();
    #pragma unroll
    for (int ks=0; ks<2; ks++){
      const int kq = ks*32 + (lane>>4)*8;
      bf16x8 af[4], bfr[4];
      #pragma unroll
      for (int i=0;i<4;i++){
        af[i]  = *(const bf16x8*)(As + (wm + i*16 + r)*64 + kq);
        bfr[i] = *(const bf16x8*)(Bs + (wn + i*16 + r)*64 + kq);
      }
      #pragma unroll
      for (int i=0;i<4;i++)
        #pragma unroll
        for (int n2=0;n2<4;n2++)
          acc[i][n2] = __builtin_amdgcn_mfma_f32_16x16x32_bf16(af[i], bfr[n2], acc[i][n2], 0,0,0);
    }
    __syncthreads();
  }
  const int crow = (lane>>4)*4, ccol = lane & 15;
  #pragma unroll
  for (int i=0;i<4;i++)
    #pragma unroll
    for (int n2=0;n2<4;n2++)
      #pragma unroll
      for (int q=0;q<4;q++)
        Cp[(size_t)(bm + wm + i*16 + crow + q)*N + (bn + wn + n2*16 + ccol)] = acc[i][n2][q];
}

// sum split-K partials + bias + relu -> bf16
__global__ __launch_bounds__(256) void bias_relu_cvt(const float* __restrict__ Ca,
    const float* __restrict__ Cb, const float* __restrict__ bias,
    unsigned short* __restrict__ Hout)
{
  int idx = blockIdx.x*256 + threadIdx.x;       // float4 index, 1M total
  float4 a = ((const float4*)Ca)[idx];
  float4 b = ((const float4*)Cb)[idx];
  float4 bs = ((const float4*)bias)[idx & 255]; // 1024/4 bias vectors
  ushort4 o;
  o.x = f2bf(fmaxf(a.x+b.x+bs.x, 0.f));
  o.y = f2bf(fmaxf(a.y+b.y+bs.y, 0.f));
  o.z = f2bf(fmaxf(a.z+b.z+bs.z, 0.f));
  o.w = f2bf(fmaxf(a.w+b.w+bs.w, 0.f));
  ((ushort4*)Hout)[idx] = o;
}

// ---------------------------------------------------------------------------
// Fused heads + losses: per 16-row block compute logits/reg in LDS, then
// per-row CE + masked smooth-L1, deterministic block partial reduce.
// ---------------------------------------------------------------------------
__global__ __launch_bounds__(256) void head_loss(const unsigned short* __restrict__ H2,
    const unsigned short* __restrict__ W3T, const float* __restrict__ clsb,
    const float* __restrict__ regb, const int* __restrict__ labels,
    const float* __restrict__ targets, float* __restrict__ partials)
{
  __shared__ unsigned short hs[16*1032];        // +8 pad breaks bank conflicts
  __shared__ float outs[16][97];                // 96 cols + pad
  __shared__ float red[32];
  int t = threadIdx.x;
  int r0 = blockIdx.x * 16;
  for (int c = t; c < 2048; c += 256){
    int row = c >> 7;
    int col = (c & 127) * 8;
    *(uint4*)(hs + row*1032 + col) = *(const uint4*)(H2 + (size_t)(r0+row)*1024 + col);
  }
  __syncthreads();
  int r = t & 15;
  int nb = (t >> 4) * 6;
  float acc[6] = {0,0,0,0,0,0};
  for (int k = 0; k < 1024; k += 8){
    bf16x8 hv = *(const bf16x8*)(hs + r*1032 + k);
    float hf[8];
    #pragma unroll
    for (int e=0;e<8;e++) hf[e] = bf2f((unsigned short)hv[e]);
    #pragma unroll
    for (int j=0;j<6;j++){
      bf16x8 wv = *(const bf16x8*)(W3T + (size_t)(nb+j)*1024 + k);
      #pragma unroll
      for (int e=0;e<8;e++) acc[j] += hf[e] * bf2f((unsigned short)wv[e]);
    }
  }
  #pragma unroll
  for (int j=0;j<6;j++){
    int n = nb + j;
    float bias = (n<16) ? clsb[n] : regb[n-16];
    outs[r][n] = acc[j] + bias;
  }
  __syncthreads();
  if (t < 16){
    const float* o = outs[t];
    int lab = labels[r0 + t];
    float m = o[0];
    #pragma unroll
    for (int j=1;j<16;j++) m = fmaxf(m, o[j]);
    float s = 0.f;
    #pragma unroll
    for (int j=0;j<16;j++) s += expf(o[j]-m);
    float lc = logf(s) + m - o[(lab < 0) ? (lab + 16) : lab];
    float lr = 0.f;
    if (lab > 0){
      const float* tg = targets + (size_t)(r0+t)*5;
      #pragma unroll
      for (int j=0;j<5;j++){
        float d = fabsf(o[16 + lab*5 + j] - tg[j]);
        lr += (d < (1.f/9.f)) ? (4.5f*d*d) : (d - (1.f/18.f));
      }
    }
    red[t] = lc; red[16+t] = lr;
  }
  __syncthreads();
  if (t == 0){
    float a = 0.f, b = 0.f;
    #pragma unroll
    for (int i=0;i<16;i++){ a += red[i]; b += red[16+i]; }
    partials[blockIdx.x*2]   = a;
    partials[blockIdx.x*2+1] = b;
  }
}

__global__ void loss_final(const float* __restrict__ partials, float* __restrict__ out){
  if (threadIdx.x == 0){
    float a = 0.f, b = 0.f;
    for (int i=0;i<256;i++){ a += partials[2*i]; b += partials[2*i+1]; }
    out[0] = a * (1.f/4096.f);
    out[1] = b * (1.f/4096.f);
  }
}

// ---------------------------------------------------------------------------
extern "C" void kernel_launch(void* const* d_in, const int* in_sizes, int n_in,
                              void* d_out, int out_size, void* d_ws, size_t ws_size,
                              hipStream_t stream)
{
  const float* proposals = (const float*)d_in[0];
  const float* gtb  = (const float*)d_in[1];
  const float* gto  = (const float*)d_in[2];
  const int*   gtl  = (const int*)d_in[3];
  const float* feat = (const float*)d_in[4];
  const float* fc1w = (const float*)d_in[5];
  const float* fc1b = (const float*)d_in[6];
  const float* fc2w = (const float*)d_in[7];
  const float* fc2b = (const float*)d_in[8];
  const float* clsw = (const float*)d_in[9];
  const float* clsb = (const float*)d_in[10];
  const float* regw = (const float*)d_in[11];
  const float* regb = (const float*)d_in[12];

  unsigned char* p = (unsigned char*)d_ws;
  auto alloc = [&](size_t bytes)->unsigned char*{
    unsigned char* r = p; p += (bytes + 255) & ~(size_t)255; return r;
  };
  unsigned short* W1T = (unsigned short*)alloc((size_t)1024*12544*2);
  unsigned short* W2T = (unsigned short*)alloc((size_t)1024*1024*2);
  unsigned short* W3T = (unsigned short*)alloc((size_t)96*1024*2);
  float*          C   = (float*)alloc((size_t)2*4096*1024*4);   // split-K partials
  unsigned short* H1  = (unsigned short*)alloc((size_t)4096*1024*2);
  unsigned short* H2  = (unsigned short*)alloc((size_t)4096*1024*2);
  float*       targets= (float*)alloc((size_t)4096*5*4);
  int*          labels= (int*)alloc((size_t)4096*4);
  int*            rows= (int*)alloc((size_t)4096*4);
  float*      partials= (float*)alloc((size_t)256*2*4);

  match_sample_kernel<<<8, 256, 0, stream>>>(proposals, gtb, gto, gtl, rows, labels, targets);
  transpose_cvt<<<dim3(392,32), dim3(32,8), 0, stream>>>(fc1w, W1T, 12544, 1024);
  transpose_cvt<<<dim3(32,32),  dim3(32,8), 0, stream>>>(fc2w, W2T, 1024, 1024);
  w3_cvt<<<96, 256, 0, stream>>>(clsw, regw, W3T);

  gemm_fc1<<<dim3(32,8,2), 256, 0, stream>>>(feat, rows, W1T, C, 12544, 6272, (size_t)4096*1024);
  bias_relu_cvt<<<4096, 256, 0, stream>>>(C, C + (size_t)4096*1024, fc1b, H1);

  gemm_bf16<<<dim3(32,8,2), 256, 0, stream>>>(H1, W2T, C, 1024, 512, (size_t)4096*1024);
  bias_relu_cvt<<<4096, 256, 0, stream>>>(C, C + (size_t)4096*1024, fc2b, H2);

  head_loss<<<256, 256, 0, stream>>>(H2, W3T, clsb, regb, labels, targets, partials);
  loss_final<<<1, 64, 0, stream>>>(partials, (float*)d_out);
}